// Round 1
// baseline (277.285 us; speedup 1.0000x reference)
//
#include <hip/hip_runtime.h>

#define SLEN 1024
#define DDIM 64
#define NPOS 64
#define QROWS 8
#define KTILE 128
#define KPAD 68            // padded k-tile row stride (floats); b128 reads bank-balanced
#define NTILES (SLEN / KTILE)
#define COPE_SCALE 0.125f

__global__ __launch_bounds__(256) void cope_kernel(
    const float* __restrict__ q,
    const float* __restrict__ k,
    const float* __restrict__ pos_emb,
    const int*   __restrict__ is_cope_k,
    float*       __restrict__ out)
{
    // smem is the k-tile buffer during Phase B (128*68*4 = 34816 B),
    // then reused as the gate matrix G[8][1024] (32768 B) afterwards.
    __shared__ __align__(16) float smem[KTILE * KPAD];
    __shared__ __align__(16) float qT[DDIM][QROWS];     // qT[d][r]
    __shared__ __align__(16) float baseT[DDIM][QROWS];  // base rows for table
    __shared__ __align__(16) float tableL[QROWS][NPOS];

    const int t = threadIdx.x;
    const int blk = blockIdx.x;
    const int batch = blk / (SLEN / QROWS);
    const int qbase = (blk % (SLEN / QROWS)) * QROWS;

    const float* bsrc = (*is_cope_k) ? q : k;

    // ---------------- Phase A: stage q (transposed) + base rows ----------------
    for (int i = t; i < QROWS * DDIM; i += 256) {
        int r = i >> 6, d = i & 63;
        size_t gi = (size_t)(batch * SLEN + qbase + r) * DDIM + d;
        qT[d][r] = q[gi];
        baseT[d][r] = bsrc[gi];
    }
    __syncthreads();

    // table: tableL[r][n] = sum_d base[r][d] * pos_emb[d][n]
    for (int i = t; i < QROWS * NPOS; i += 256) {
        int r = i >> 6, n = i & 63;
        float a = 0.f;
        #pragma unroll
        for (int d = 0; d < DDIM; ++d)
            a += baseT[d][r] * pos_emb[d * NPOS + n];
        tableL[r][n] = a;  // consumed only in Phase D (after barriers)
    }

    // ---------------- Phase B: QK^T ----------------
    const int jl = t & 127;   // j within k-tile
    const int qg = t >> 7;    // 0/1 -> q rows qg*4 .. qg*4+3
    float acc[4][NTILES];
    #pragma unroll
    for (int r = 0; r < 4; ++r)
        #pragma unroll
        for (int tl = 0; tl < NTILES; ++tl) acc[r][tl] = 0.f;

    float (*kT)[KPAD] = (float (*)[KPAD])smem;
    const float* kbatch = k + (size_t)batch * SLEN * DDIM;

    #pragma unroll
    for (int tile = 0; tile < NTILES; ++tile) {
        __syncthreads();  // previous tile's reads done before overwrite
        const float4* src = (const float4*)(kbatch + tile * KTILE * DDIM);
        #pragma unroll
        for (int i = 0; i < (KTILE * DDIM / 4) / 256; ++i) {  // 8 float4 per thread
            int idx = i * 256 + t;
            int row = (idx * 4) >> 6;
            int col = (idx * 4) & 63;
            float4 vv = src[idx];
            *(float4*)&kT[row][col] = vv;
        }
        __syncthreads();
        #pragma unroll
        for (int d = 0; d < DDIM; d += 4) {
            float4 kv = *(const float4*)&kT[jl][d];
            float4 q0 = *(const float4*)&qT[d + 0][qg * 4];  // broadcast (wave-uniform)
            float4 q1 = *(const float4*)&qT[d + 1][qg * 4];
            float4 q2 = *(const float4*)&qT[d + 2][qg * 4];
            float4 q3 = *(const float4*)&qT[d + 3][qg * 4];
            acc[0][tile] += kv.x * q0.x + kv.y * q1.x + kv.z * q2.x + kv.w * q3.x;
            acc[1][tile] += kv.x * q0.y + kv.y * q1.y + kv.z * q2.y + kv.w * q3.y;
            acc[2][tile] += kv.x * q0.z + kv.y * q1.z + kv.z * q2.z + kv.w * q3.z;
            acc[3][tile] += kv.x * q0.w + kv.y * q1.w + kv.z * q2.w + kv.w * q3.w;
        }
    }

    // ---------------- Phase C: sigmoid + write gates ----------------
    __syncthreads();  // all kT reads complete before G overwrites smem
    float (*G)[SLEN] = (float (*)[SLEN])smem;
    #pragma unroll
    for (int r = 0; r < 4; ++r) {
        #pragma unroll
        for (int tl = 0; tl < NTILES; ++tl) {
            float x = acc[r][tl] * COPE_SCALE;
            float e = __expf(-x);
            G[qg * 4 + r][tl * KTILE + jl] = 1.0f / (1.0f + e);
        }
    }
    __syncthreads();

    // ---------------- Phase D: reverse cumsum + interpolation + store ----------
    const int wave = t >> 6;
    const int lane = t & 63;
    #pragma unroll
    for (int rep = 0; rep < 2; ++rep) {
        const int row = wave * 2 + rep;  // rows 0..7
        // lane handles j = s*256 + lane*4 + i  (s=0..3, i=0..3)
        float g4[4][4];
        #pragma unroll
        for (int s = 0; s < 4; ++s) {
            float4 v = *(const float4*)&G[row][s * 256 + lane * 4];
            g4[s][0] = v.x; g4[s][1] = v.y; g4[s][2] = v.z; g4[s][3] = v.w;
        }
        // local suffix within each 4-group
        float ls[4][4], T[4];
        #pragma unroll
        for (int s = 0; s < 4; ++s) {
            float a = 0.f;
            #pragma unroll
            for (int i = 3; i >= 0; --i) { a += g4[s][i]; ls[s][i] = a; }
            T[s] = a;
        }
        // wave-level suffix scan of group totals, per segment
        float E[4], Stot[4];
        #pragma unroll
        for (int s = 0; s < 4; ++s) {
            float v = T[s];
            #pragma unroll
            for (int ofs = 1; ofs < 64; ofs <<= 1) {
                float u = __shfl_down(v, ofs);
                if (lane + ofs < 64) v += u;
            }
            E[s] = v - T[s];          // sum over lanes > this lane, same segment
            Stot[s] = __shfl(v, 0);   // segment total
        }
        float segOff[4];
        segOff[3] = 0.f;
        segOff[2] = Stot[3];
        segOff[1] = Stot[3] + Stot[2];
        segOff[0] = Stot[3] + Stot[2] + Stot[1];

        const float* tab = tableL[row];
        float* orow = out + (size_t)(batch * SLEN + qbase + row) * SLEN;
        #pragma unroll
        for (int s = 0; s < 4; ++s) {
            float res[4];
            #pragma unroll
            for (int i = 0; i < 4; ++i) {
                float p = ls[s][i] + E[s] + segOff[s];
                p = fminf(p, (float)(NPOS - 1));
                float pf = floorf(p);
                int fi = (int)pf;
                int ci = (int)ceilf(p);
                float w = p - pf;
                float lo = tab[fi], hi = tab[ci];
                res[i] = hi * w + lo * (1.0f - w);
            }
            float4 o; o.x = res[0]; o.y = res[1]; o.z = res[2]; o.w = res[3];
            *(float4*)&orow[s * 256 + lane * 4] = o;
        }
    }
}

extern "C" void kernel_launch(void* const* d_in, const int* in_sizes, int n_in,
                              void* d_out, int out_size, void* d_ws, size_t ws_size,
                              hipStream_t stream) {
    const float* q        = (const float*)d_in[0];
    const float* k        = (const float*)d_in[1];
    // d_in[2] = v      (unused by reference mode 0)
    const float* pos_emb  = (const float*)d_in[3];
    // d_in[4] = w_k    (unused by reference)
    const int*   is_cope_k = (const int*)d_in[5];
    float* out = (float*)d_out;

    const int B = in_sizes[0] / (SLEN * DDIM);
    dim3 grid(B * (SLEN / QROWS));
    cope_kernel<<<grid, 256, 0, stream>>>(q, k, pos_emb, is_cope_k, out);
}

// Round 2
// 237.805 us; speedup vs baseline: 1.1660x; 1.1660x over previous
//
#include <hip/hip_runtime.h>

#define SLEN 1024
#define DDIM 64
#define NPOS 64
#define QROWS 16
#define COPE_SCALE 0.125f

typedef __bf16 bf16x8 __attribute__((ext_vector_type(8)));
typedef float f32x4 __attribute__((ext_vector_type(4)));

__device__ __forceinline__ unsigned short f2bf_hi(float x) {
    unsigned u = __builtin_bit_cast(unsigned, x);
    unsigned r = u + 0x7FFFu + ((u >> 16) & 1u);
    return (unsigned short)(r >> 16);
}
__device__ __forceinline__ float bf2f(unsigned short h) {
    unsigned u = ((unsigned)h) << 16;
    return __builtin_bit_cast(float, u);
}

// ---------------- prep: split k into bf16 hi + lo ----------------
__global__ __launch_bounds__(256) void prep_kernel(
    const float* __restrict__ k,
    unsigned short* __restrict__ khi,
    unsigned short* __restrict__ klo,
    int n4)
{
    int i = blockIdx.x * 256 + threadIdx.x;
    if (i >= n4) return;
    float4 v = ((const float4*)k)[i];
    ushort4 h, l;
    h.x = f2bf_hi(v.x); l.x = f2bf_hi(v.x - bf2f(h.x));
    h.y = f2bf_hi(v.y); l.y = f2bf_hi(v.y - bf2f(h.y));
    h.z = f2bf_hi(v.z); l.z = f2bf_hi(v.z - bf2f(h.z));
    h.w = f2bf_hi(v.w); l.w = f2bf_hi(v.w - bf2f(h.w));
    ((ushort4*)khi)[i] = h;
    ((ushort4*)klo)[i] = l;
}

// ---------------- main MFMA kernel ----------------
__global__ __launch_bounds__(256) void cope_mfma_kernel(
    const float* __restrict__ q,
    const float* __restrict__ k,
    const float* __restrict__ pos_emb,
    const int*   __restrict__ is_cope_k,
    const unsigned short* __restrict__ khi,
    const unsigned short* __restrict__ klo,
    float*       __restrict__ out)
{
    __shared__ __align__(16) float G[QROWS][SLEN];      // 64 KB gates
    __shared__ __align__(16) float baseT[DDIM][17];     // padded
    __shared__ __align__(16) float tableL[QROWS][NPOS];

    const int t = threadIdx.x;
    const int blk = blockIdx.x;
    const int batch = blk / (SLEN / QROWS);
    const int qbase = (blk % (SLEN / QROWS)) * QROWS;

    const float* bsrc = (*is_cope_k) ? q : k;

    // ---- Phase A1: stage base rows (transposed) ----
    for (int i = t; i < QROWS * DDIM; i += 256) {
        int r = i >> 6, d = i & 63;
        baseT[d][r] = bsrc[(size_t)(batch * SLEN + qbase + r) * DDIM + d];
    }
    __syncthreads();

    // ---- Phase A2: interp table tableL[r][n] = sum_d base[r][d]*pos_emb[d][n] ----
    for (int i = t; i < QROWS * NPOS; i += 256) {
        int r = i >> 6, n = i & 63;
        float a = 0.f;
        #pragma unroll
        for (int d = 0; d < DDIM; ++d)
            a += baseT[d][r] * pos_emb[d * NPOS + n];
        tableL[r][n] = a;
    }

    // ---- Phase B: QK^T via split-bf16 MFMA ----
    const int wave = t >> 6;
    const int lane = t & 63;
    const int quad = lane >> 4;
    const int nloc = lane & 15;

    // A fragments: q rows qbase..qbase+15, lane holds A[m=nloc][k=quad*8+j+ks*32]
    bf16x8 a_hi[2], a_lo[2];
    {
        const float* qrow = q + (size_t)(batch * SLEN + qbase + nloc) * DDIM + quad * 8;
        #pragma unroll
        for (int ks = 0; ks < 2; ++ks) {
            float4 v0 = *(const float4*)(qrow + ks * 32);
            float4 v1 = *(const float4*)(qrow + ks * 32 + 4);
            float xs[8] = {v0.x, v0.y, v0.z, v0.w, v1.x, v1.y, v1.z, v1.w};
            unsigned short hb[8], lb[8];
            #pragma unroll
            for (int j = 0; j < 8; ++j) {
                hb[j] = f2bf_hi(xs[j]);
                lb[j] = f2bf_hi(xs[j] - bf2f(hb[j]));
            }
            ushort4 h0 = {hb[0], hb[1], hb[2], hb[3]}, h1 = {hb[4], hb[5], hb[6], hb[7]};
            ushort4 l0 = {lb[0], lb[1], lb[2], lb[3]}, l1 = {lb[4], lb[5], lb[6], lb[7]};
            struct U8 { ushort4 a, b; };
            U8 hh = {h0, h1}, ll = {l0, l1};
            a_hi[ks] = __builtin_bit_cast(bf16x8, hh);
            a_lo[ks] = __builtin_bit_cast(bf16x8, ll);
        }
    }

    // each wave: 16 n-tiles (cols wave*256 .. wave*256+255)
    #pragma unroll 4
    for (int i = 0; i < 16; ++i) {
        int tile = wave * 16 + i;
        size_t boff = (size_t)(batch * SLEN + tile * 16 + nloc) * DDIM + quad * 8;
        // B fragments: lane holds B[k=quad*8+j+ks*32][n=nloc] = k[n][k-range] (b128)
        uint4 bh0 = *(const uint4*)(khi + boff);
        uint4 bh1 = *(const uint4*)(khi + boff + 32);
        uint4 bl0 = *(const uint4*)(klo + boff);
        uint4 bl1 = *(const uint4*)(klo + boff + 32);
        f32x4 acc = {0.f, 0.f, 0.f, 0.f};
        acc = __builtin_amdgcn_mfma_f32_16x16x32_bf16(a_hi[0], __builtin_bit_cast(bf16x8, bh0), acc, 0, 0, 0);
        acc = __builtin_amdgcn_mfma_f32_16x16x32_bf16(a_lo[0], __builtin_bit_cast(bf16x8, bh0), acc, 0, 0, 0);
        acc = __builtin_amdgcn_mfma_f32_16x16x32_bf16(a_hi[0], __builtin_bit_cast(bf16x8, bl0), acc, 0, 0, 0);
        acc = __builtin_amdgcn_mfma_f32_16x16x32_bf16(a_hi[1], __builtin_bit_cast(bf16x8, bh1), acc, 0, 0, 0);
        acc = __builtin_amdgcn_mfma_f32_16x16x32_bf16(a_lo[1], __builtin_bit_cast(bf16x8, bh1), acc, 0, 0, 0);
        acc = __builtin_amdgcn_mfma_f32_16x16x32_bf16(a_hi[1], __builtin_bit_cast(bf16x8, bl1), acc, 0, 0, 0);
        // sigmoid + scatter to G; C/D: col=lane&15 (=n), row=quad*4+reg (=m)
        #pragma unroll
        for (int reg = 0; reg < 4; ++reg) {
            float x = acc[reg] * COPE_SCALE;
            float g = 1.0f / (1.0f + __expf(-x));
            G[quad * 4 + reg][tile * 16 + nloc] = g;
        }
    }
    __syncthreads();

    // ---- Phase D: reverse cumsum + interpolation + store ----
    #pragma unroll
    for (int rep = 0; rep < 4; ++rep) {
        const int row = wave * 4 + rep;  // rows 0..15
        float g4[4][4];
        #pragma unroll
        for (int s = 0; s < 4; ++s) {
            float4 v = *(const float4*)&G[row][s * 256 + lane * 4];
            g4[s][0] = v.x; g4[s][1] = v.y; g4[s][2] = v.z; g4[s][3] = v.w;
        }
        float ls[4][4], T[4];
        #pragma unroll
        for (int s = 0; s < 4; ++s) {
            float a = 0.f;
            #pragma unroll
            for (int i = 3; i >= 0; --i) { a += g4[s][i]; ls[s][i] = a; }
            T[s] = a;
        }
        float E[4], Stot[4];
        #pragma unroll
        for (int s = 0; s < 4; ++s) {
            float v = T[s];
            #pragma unroll
            for (int ofs = 1; ofs < 64; ofs <<= 1) {
                float u = __shfl_down(v, ofs);
                if (lane + ofs < 64) v += u;
            }
            E[s] = v - T[s];
            Stot[s] = __shfl(v, 0);
        }
        float segOff[4];
        segOff[3] = 0.f;
        segOff[2] = Stot[3];
        segOff[1] = Stot[3] + Stot[2];
        segOff[0] = Stot[3] + Stot[2] + Stot[1];

        const float* tab = tableL[row];
        float* orow = out + (size_t)(batch * SLEN + qbase + row) * SLEN;
        #pragma unroll
        for (int s = 0; s < 4; ++s) {
            float res[4];
            #pragma unroll
            for (int i = 0; i < 4; ++i) {
                float p = ls[s][i] + E[s] + segOff[s];
                p = fminf(p, (float)(NPOS - 1));
                float pf = floorf(p);
                int fi = (int)pf;
                int ci = (int)ceilf(p);
                float w = p - pf;
                float lo = tab[fi], hi = tab[ci];
                res[i] = hi * w + lo * (1.0f - w);
            }
            float4 o; o.x = res[0]; o.y = res[1]; o.z = res[2]; o.w = res[3];
            *(float4*)&orow[s * 256 + lane * 4] = o;
        }
    }
}

// ---------------- fallback: round-1 fp32 kernel (used if ws too small) ----------------
#define KTILE 128
#define KPAD 68
#define NTILES (SLEN / KTILE)
#define FQROWS 8

__global__ __launch_bounds__(256) void cope_fallback(
    const float* __restrict__ q,
    const float* __restrict__ k,
    const float* __restrict__ pos_emb,
    const int*   __restrict__ is_cope_k,
    float*       __restrict__ out)
{
    __shared__ __align__(16) float smem[KTILE * KPAD];
    __shared__ __align__(16) float qT[DDIM][FQROWS];
    __shared__ __align__(16) float baseT[DDIM][FQROWS];
    __shared__ __align__(16) float tableL[FQROWS][NPOS];

    const int t = threadIdx.x;
    const int blk = blockIdx.x;
    const int batch = blk / (SLEN / FQROWS);
    const int qbase = (blk % (SLEN / FQROWS)) * FQROWS;
    const float* bsrc = (*is_cope_k) ? q : k;

    for (int i = t; i < FQROWS * DDIM; i += 256) {
        int r = i >> 6, d = i & 63;
        size_t gi = (size_t)(batch * SLEN + qbase + r) * DDIM + d;
        qT[d][r] = q[gi];
        baseT[d][r] = bsrc[gi];
    }
    __syncthreads();
    for (int i = t; i < FQROWS * NPOS; i += 256) {
        int r = i >> 6, n = i & 63;
        float a = 0.f;
        #pragma unroll
        for (int d = 0; d < DDIM; ++d) a += baseT[d][r] * pos_emb[d * NPOS + n];
        tableL[r][n] = a;
    }
    const int jl = t & 127;
    const int qg = t >> 7;
    float acc[4][NTILES];
    #pragma unroll
    for (int r = 0; r < 4; ++r)
        #pragma unroll
        for (int tl = 0; tl < NTILES; ++tl) acc[r][tl] = 0.f;
    float (*kT)[KPAD] = (float (*)[KPAD])smem;
    const float* kbatch = k + (size_t)batch * SLEN * DDIM;
    #pragma unroll
    for (int tile = 0; tile < NTILES; ++tile) {
        __syncthreads();
        const float4* src = (const float4*)(kbatch + tile * KTILE * DDIM);
        #pragma unroll
        for (int i = 0; i < (KTILE * DDIM / 4) / 256; ++i) {
            int idx = i * 256 + t;
            int row = (idx * 4) >> 6;
            int col = (idx * 4) & 63;
            float4 vv = src[idx];
            *(float4*)&kT[row][col] = vv;
        }
        __syncthreads();
        #pragma unroll
        for (int d = 0; d < DDIM; d += 4) {
            float4 kv = *(const float4*)&kT[jl][d];
            float4 q0 = *(const float4*)&qT[d + 0][qg * 4];
            float4 q1 = *(const float4*)&qT[d + 1][qg * 4];
            float4 q2 = *(const float4*)&qT[d + 2][qg * 4];
            float4 q3 = *(const float4*)&qT[d + 3][qg * 4];
            acc[0][tile] += kv.x * q0.x + kv.y * q1.x + kv.z * q2.x + kv.w * q3.x;
            acc[1][tile] += kv.x * q0.y + kv.y * q1.y + kv.z * q2.y + kv.w * q3.y;
            acc[2][tile] += kv.x * q0.z + kv.y * q1.z + kv.z * q2.z + kv.w * q3.z;
            acc[3][tile] += kv.x * q0.w + kv.y * q1.w + kv.z * q2.w + kv.w * q3.w;
        }
    }
    __syncthreads();
    float (*G)[SLEN] = (float (*)[SLEN])smem;
    #pragma unroll
    for (int r = 0; r < 4; ++r)
        #pragma unroll
        for (int tl = 0; tl < NTILES; ++tl) {
            float x = acc[r][tl] * COPE_SCALE;
            G[qg * 4 + r][tl * KTILE + jl] = 1.0f / (1.0f + __expf(-x));
        }
    __syncthreads();
    const int wave = t >> 6;
    const int lane = t & 63;
    #pragma unroll
    for (int rep = 0; rep < 2; ++rep) {
        const int row = wave * 2 + rep;
        float g4[4][4];
        #pragma unroll
        for (int s = 0; s < 4; ++s) {
            float4 v = *(const float4*)&G[row][s * 256 + lane * 4];
            g4[s][0] = v.x; g4[s][1] = v.y; g4[s][2] = v.z; g4[s][3] = v.w;
        }
        float ls[4][4], T[4];
        #pragma unroll
        for (int s = 0; s < 4; ++s) {
            float a = 0.f;
            #pragma unroll
            for (int i = 3; i >= 0; --i) { a += g4[s][i]; ls[s][i] = a; }
            T[s] = a;
        }
        float E[4], Stot[4];
        #pragma unroll
        for (int s = 0; s < 4; ++s) {
            float v = T[s];
            #pragma unroll
            for (int ofs = 1; ofs < 64; ofs <<= 1) {
                float u = __shfl_down(v, ofs);
                if (lane + ofs < 64) v += u;
            }
            E[s] = v - T[s];
            Stot[s] = __shfl(v, 0);
        }
        float segOff[4];
        segOff[3] = 0.f;
        segOff[2] = Stot[3];
        segOff[1] = Stot[3] + Stot[2];
        segOff[0] = Stot[3] + Stot[2] + Stot[1];
        const float* tab = tableL[row];
        float* orow = out + (size_t)(batch * SLEN + qbase + row) * SLEN;
        #pragma unroll
        for (int s = 0; s < 4; ++s) {
            float res[4];
            #pragma unroll
            for (int i = 0; i < 4; ++i) {
                float p = ls[s][i] + E[s] + segOff[s];
                p = fminf(p, (float)(NPOS - 1));
                float pf = floorf(p);
                int fi = (int)pf;
                int ci = (int)ceilf(p);
                float w = p - pf;
                res[i] = tab[ci] * w + tab[fi] * (1.0f - w);
            }
            float4 o; o.x = res[0]; o.y = res[1]; o.z = res[2]; o.w = res[3];
            *(float4*)&orow[s * 256 + lane * 4] = o;
        }
    }
}

extern "C" void kernel_launch(void* const* d_in, const int* in_sizes, int n_in,
                              void* d_out, int out_size, void* d_ws, size_t ws_size,
                              hipStream_t stream) {
    const float* q        = (const float*)d_in[0];
    const float* k        = (const float*)d_in[1];
    const float* pos_emb  = (const float*)d_in[3];
    const int*   is_cope_k = (const int*)d_in[5];
    float* out = (float*)d_out;

    const int nk = in_sizes[1];                 // B*S*D
    const int B = in_sizes[0] / (SLEN * DDIM);
    const size_t ws_need = (size_t)nk * 2 * sizeof(unsigned short);  // khi + klo

    if (ws_size >= ws_need) {
        unsigned short* khi = (unsigned short*)d_ws;
        unsigned short* klo = khi + nk;
        int n4 = nk / 4;
        prep_kernel<<<(n4 + 255) / 256, 256, 0, stream>>>(k, khi, klo, n4);
        cope_mfma_kernel<<<B * (SLEN / QROWS), 256, 0, stream>>>(
            q, k, pos_emb, is_cope_k, khi, klo, out);
    } else {
        cope_fallback<<<B * (SLEN / FQROWS), 256, 0, stream>>>(
            q, k, pos_emb, is_cope_k, out);
    }
}

// Round 3
// 211.504 us; speedup vs baseline: 1.3110x; 1.1244x over previous
//
#include <hip/hip_runtime.h>

#define SLEN 1024
#define DDIM 64
#define NPOS 64
#define QROWS 16
#define COPE_SCALE 0.125f
#define GSTR 524   // fp32 words per G row: 512 data + 12 pad (4*524 % 32 == 16 -> 2-way max on scatter stores; 16B-aligned rows)
#define TSTR 66    // table row stride (4*66 % 32 == 8 -> conflict-free scatter)

typedef __bf16 bf16x8 __attribute__((ext_vector_type(8)));
typedef float f32x4 __attribute__((ext_vector_type(4)));

__device__ __forceinline__ unsigned short f2bf_hi(float x) {
    unsigned u = __builtin_bit_cast(unsigned, x);
    unsigned r = u + 0x7FFFu + ((u >> 16) & 1u);
    return (unsigned short)(r >> 16);
}
__device__ __forceinline__ float bf2f(unsigned short h) {
    unsigned u = ((unsigned)h) << 16;
    return __builtin_bit_cast(float, u);
}
struct U8 { ushort4 a, b; };
__device__ __forceinline__ bf16x8 pack8(const unsigned short* s) {
    U8 u = {{s[0], s[1], s[2], s[3]}, {s[4], s[5], s[6], s[7]}};
    return __builtin_bit_cast(bf16x8, u);
}

// ---------------- prep: split k into bf16 hi + lo ----------------
__global__ __launch_bounds__(256) void prep_kernel(
    const float* __restrict__ k,
    unsigned short* __restrict__ khi,
    unsigned short* __restrict__ klo,
    int n4)
{
    int i = blockIdx.x * 256 + threadIdx.x;
    if (i >= n4) return;
    float4 v = ((const float4*)k)[i];
    ushort4 h, l;
    h.x = f2bf_hi(v.x); l.x = f2bf_hi(v.x - bf2f(h.x));
    h.y = f2bf_hi(v.y); l.y = f2bf_hi(v.y - bf2f(h.y));
    h.z = f2bf_hi(v.z); l.z = f2bf_hi(v.z - bf2f(h.z));
    h.w = f2bf_hi(v.w); l.w = f2bf_hi(v.w - bf2f(h.w));
    ((ushort4*)khi)[i] = h;
    ((ushort4*)klo)[i] = l;
}

// ---------------- main MFMA kernel ----------------
__global__ __launch_bounds__(256, 4) void cope_mfma_kernel(
    const float* __restrict__ q,
    const float* __restrict__ k,
    const float* __restrict__ pos_emb,
    const int*   __restrict__ is_cope_k,
    const unsigned short* __restrict__ khi,
    const unsigned short* __restrict__ klo,
    float*       __restrict__ out)
{
    __shared__ __align__(16) float G[QROWS * GSTR];        // 33.5 KB (half of S at a time)
    __shared__ __align__(16) float tableL[QROWS * TSTR];   // 4.2 KB
    __shared__ float rowTot[QROWS];

    const int t = threadIdx.x;
    const int wave = t >> 6;
    const int lane = t & 63;
    const int quad = lane >> 4;
    const int nloc = lane & 15;
    const int blk = blockIdx.x;
    const int batch = blk >> 6;           // SLEN/QROWS = 64 blocks per batch
    const int qbase = (blk & 63) * QROWS;

    // ---- A fragments from q (split hi/lo): lane holds A[m=nloc][k=quad*8+j+ks*32] ----
    bf16x8 a_hi[2], a_lo[2];
    {
        const float* qrow = q + (size_t)(batch * SLEN + qbase + nloc) * DDIM + quad * 8;
        #pragma unroll
        for (int ks = 0; ks < 2; ++ks) {
            float4 v0 = *(const float4*)(qrow + ks * 32);
            float4 v1 = *(const float4*)(qrow + ks * 32 + 4);
            float xs[8] = {v0.x, v0.y, v0.z, v0.w, v1.x, v1.y, v1.z, v1.w};
            unsigned short hb[8], lb[8];
            #pragma unroll
            for (int j = 0; j < 8; ++j) {
                hb[j] = f2bf_hi(xs[j]);
                lb[j] = f2bf_hi(xs[j] - bf2f(hb[j]));
            }
            a_hi[ks] = pack8(hb);
            a_lo[ks] = pack8(lb);
        }
    }

    // ---- interp table via MFMA: table[m][n] = sum_d base[m][d] * pos_emb[d][n] ----
    // wave w computes n-tile w*16..w*16+15. A = base rows (split), B = pos_emb (hi only).
    {
        const int icope = *is_cope_k;   // wave-uniform
        bf16x8 t_hi[2], t_lo[2];
        if (icope) {
            t_hi[0] = a_hi[0]; t_hi[1] = a_hi[1];
            t_lo[0] = a_lo[0]; t_lo[1] = a_lo[1];
        } else {
            size_t boff = (size_t)(batch * SLEN + qbase + nloc) * DDIM + quad * 8;
            t_hi[0] = __builtin_bit_cast(bf16x8, *(const uint4*)(khi + boff));
            t_hi[1] = __builtin_bit_cast(bf16x8, *(const uint4*)(khi + boff + 32));
            t_lo[0] = __builtin_bit_cast(bf16x8, *(const uint4*)(klo + boff));
            t_lo[1] = __builtin_bit_cast(bf16x8, *(const uint4*)(klo + boff + 32));
        }
        bf16x8 p_hi[2];
        #pragma unroll
        for (int ks = 0; ks < 2; ++ks) {
            unsigned short hb[8];
            #pragma unroll
            for (int j = 0; j < 8; ++j) {
                float pv = pos_emb[(quad * 8 + j + ks * 32) * NPOS + wave * 16 + nloc];
                hb[j] = f2bf_hi(pv);
            }
            p_hi[ks] = pack8(hb);
        }
        f32x4 tacc = {0.f, 0.f, 0.f, 0.f};
        tacc = __builtin_amdgcn_mfma_f32_16x16x32_bf16(t_hi[0], p_hi[0], tacc, 0, 0, 0);
        tacc = __builtin_amdgcn_mfma_f32_16x16x32_bf16(t_lo[0], p_hi[0], tacc, 0, 0, 0);
        tacc = __builtin_amdgcn_mfma_f32_16x16x32_bf16(t_hi[1], p_hi[1], tacc, 0, 0, 0);
        tacc = __builtin_amdgcn_mfma_f32_16x16x32_bf16(t_lo[1], p_hi[1], tacc, 0, 0, 0);
        #pragma unroll
        for (int reg = 0; reg < 4; ++reg)
            tableL[(quad * 4 + reg) * TSTR + wave * 16 + nloc] = tacc[reg];
    }

    // ---- two-pass over key halves: right (cols 512..1023) first, then left ----
    for (int half = 1; half >= 0; --half) {
        // Phase B: QK^T for this half via split-bf16 MFMA (each wave: 8 of 32 tiles)
        #pragma unroll 2
        for (int i = 0; i < 8; ++i) {
            const int tl = wave * 8 + i;           // local tile 0..31
            const int tile = half * 32 + tl;
            size_t boff = (size_t)(batch * SLEN + tile * 16 + nloc) * DDIM + quad * 8;
            uint4 bh0 = *(const uint4*)(khi + boff);
            uint4 bh1 = *(const uint4*)(khi + boff + 32);
            uint4 bl0 = *(const uint4*)(klo + boff);
            uint4 bl1 = *(const uint4*)(klo + boff + 32);
            f32x4 acc = {0.f, 0.f, 0.f, 0.f};
            acc = __builtin_amdgcn_mfma_f32_16x16x32_bf16(a_hi[0], __builtin_bit_cast(bf16x8, bh0), acc, 0, 0, 0);
            acc = __builtin_amdgcn_mfma_f32_16x16x32_bf16(a_lo[0], __builtin_bit_cast(bf16x8, bh0), acc, 0, 0, 0);
            acc = __builtin_amdgcn_mfma_f32_16x16x32_bf16(a_hi[0], __builtin_bit_cast(bf16x8, bl0), acc, 0, 0, 0);
            acc = __builtin_amdgcn_mfma_f32_16x16x32_bf16(a_hi[1], __builtin_bit_cast(bf16x8, bh1), acc, 0, 0, 0);
            acc = __builtin_amdgcn_mfma_f32_16x16x32_bf16(a_lo[1], __builtin_bit_cast(bf16x8, bh1), acc, 0, 0, 0);
            acc = __builtin_amdgcn_mfma_f32_16x16x32_bf16(a_hi[1], __builtin_bit_cast(bf16x8, bl1), acc, 0, 0, 0);
            // C/D layout: n = nloc (col), m = quad*4+reg (row)
            #pragma unroll
            for (int reg = 0; reg < 4; ++reg) {
                float x = acc[reg] * COPE_SCALE;
                float g = __builtin_amdgcn_rcpf(1.0f + __expf(-x));
                G[(quad * 4 + reg) * GSTR + tl * 16 + nloc] = g;
            }
        }
        __syncthreads();

        // Phase D: suffix scan of this half + interpolation + store (each wave: 4 rows)
        #pragma unroll
        for (int rep = 0; rep < 4; ++rep) {
            const int row = wave * 4 + rep;
            const float roff = half ? 0.f : rowTot[row];
            const float* grow = &G[row * GSTR + lane * 8];
            float4 ga = *(const float4*)grow;
            float4 gb = *(const float4*)(grow + 4);
            float g[8] = {ga.x, ga.y, ga.z, ga.w, gb.x, gb.y, gb.z, gb.w};
            float ls[8];
            float a = 0.f;
            #pragma unroll
            for (int i = 7; i >= 0; --i) { a += g[i]; ls[i] = a; }
            const float T = a;
            float v = T;
            #pragma unroll
            for (int ofs = 1; ofs < 64; ofs <<= 1) {
                float u = __shfl_down(v, ofs);
                if (lane + ofs < 64) v += u;
            }
            if (half && lane == 0) rowTot[row] = v;  // row total of right half
            const float E = v - T;                    // suffix over higher lanes

            const float tabv = tableL[row * TSTR + lane];  // table entry `lane` in lane
            float res[8];
            #pragma unroll
            for (int i = 0; i < 8; ++i) {
                float p = ls[i] + E + roff;
                p = fminf(p, (float)(NPOS - 1));
                float pf = floorf(p);
                int fi = (int)pf;
                int ci = fi < NPOS - 1 ? fi + 1 : NPOS - 1;
                float w = p - pf;
                float tf = __shfl(tabv, fi);
                float tc = __shfl(tabv, ci);
                res[i] = tc * w + tf * (1.0f - w);
            }
            float* orow = out + (size_t)(batch * SLEN + qbase + row) * SLEN + half * 512 + lane * 8;
            *(float4*)orow = *(float4*)&res[0];
            *(float4*)(orow + 4) = *(float4*)&res[4];
        }
        __syncthreads();
    }
}

// ---------------- fallback: round-1 fp32 kernel (used if ws too small) ----------------
#define KTILE 128
#define KPAD 68
#define NTILES (SLEN / KTILE)
#define FQROWS 8

__global__ __launch_bounds__(256) void cope_fallback(
    const float* __restrict__ q,
    const float* __restrict__ k,
    const float* __restrict__ pos_emb,
    const int*   __restrict__ is_cope_k,
    float*       __restrict__ out)
{
    __shared__ __align__(16) float smem[KTILE * KPAD];
    __shared__ __align__(16) float qT[DDIM][FQROWS];
    __shared__ __align__(16) float baseT[DDIM][FQROWS];
    __shared__ __align__(16) float tableL[FQROWS][NPOS];

    const int t = threadIdx.x;
    const int blk = blockIdx.x;
    const int batch = blk / (SLEN / FQROWS);
    const int qbase = (blk % (SLEN / FQROWS)) * FQROWS;
    const float* bsrc = (*is_cope_k) ? q : k;

    for (int i = t; i < FQROWS * DDIM; i += 256) {
        int r = i >> 6, d = i & 63;
        size_t gi = (size_t)(batch * SLEN + qbase + r) * DDIM + d;
        qT[d][r] = q[gi];
        baseT[d][r] = bsrc[gi];
    }
    __syncthreads();
    for (int i = t; i < FQROWS * NPOS; i += 256) {
        int r = i >> 6, n = i & 63;
        float a = 0.f;
        #pragma unroll
        for (int d = 0; d < DDIM; ++d) a += baseT[d][r] * pos_emb[d * NPOS + n];
        tableL[r][n] = a;
    }
    const int jl = t & 127;
    const int qg = t >> 7;
    float acc[4][NTILES];
    #pragma unroll
    for (int r = 0; r < 4; ++r)
        #pragma unroll
        for (int tl = 0; tl < NTILES; ++tl) acc[r][tl] = 0.f;
    float (*kT)[KPAD] = (float (*)[KPAD])smem;
    const float* kbatch = k + (size_t)batch * SLEN * DDIM;
    #pragma unroll
    for (int tile = 0; tile < NTILES; ++tile) {
        __syncthreads();
        const float4* src = (const float4*)(kbatch + tile * KTILE * DDIM);
        #pragma unroll
        for (int i = 0; i < (KTILE * DDIM / 4) / 256; ++i) {
            int idx = i * 256 + t;
            int row = (idx * 4) >> 6;
            int col = (idx * 4) & 63;
            float4 vv = src[idx];
            *(float4*)&kT[row][col] = vv;
        }
        __syncthreads();
        #pragma unroll
        for (int d = 0; d < DDIM; d += 4) {
            float4 kv = *(const float4*)&kT[jl][d];
            float4 q0 = *(const float4*)&qT[d + 0][qg * 4];
            float4 q1 = *(const float4*)&qT[d + 1][qg * 4];
            float4 q2 = *(const float4*)&qT[d + 2][qg * 4];
            float4 q3 = *(const float4*)&qT[d + 3][qg * 4];
            acc[0][tile] += kv.x * q0.x + kv.y * q1.x + kv.z * q2.x + kv.w * q3.x;
            acc[1][tile] += kv.x * q0.y + kv.y * q1.y + kv.z * q2.y + kv.w * q3.y;
            acc[2][tile] += kv.x * q0.z + kv.y * q1.z + kv.z * q2.z + kv.w * q3.z;
            acc[3][tile] += kv.x * q0.w + kv.y * q1.w + kv.z * q2.w + kv.w * q3.w;
        }
    }
    __syncthreads();
    float (*G)[SLEN] = (float (*)[SLEN])smem;
    #pragma unroll
    for (int r = 0; r < 4; ++r)
        #pragma unroll
        for (int tl = 0; tl < NTILES; ++tl) {
            float x = acc[r][tl] * COPE_SCALE;
            G[qg * 4 + r][tl * KTILE + jl] = 1.0f / (1.0f + __expf(-x));
        }
    __syncthreads();
    const int wave = t >> 6;
    const int lane = t & 63;
    #pragma unroll
    for (int rep = 0; rep < 2; ++rep) {
        const int row = wave * 2 + rep;
        float g4[4][4];
        #pragma unroll
        for (int s = 0; s < 4; ++s) {
            float4 v = *(const float4*)&G[row][s * 256 + lane * 4];
            g4[s][0] = v.x; g4[s][1] = v.y; g4[s][2] = v.z; g4[s][3] = v.w;
        }
        float ls[4][4], T[4];
        #pragma unroll
        for (int s = 0; s < 4; ++s) {
            float a = 0.f;
            #pragma unroll
            for (int i = 3; i >= 0; --i) { a += g4[s][i]; ls[s][i] = a; }
            T[s] = a;
        }
        float E[4], Stot[4];
        #pragma unroll
        for (int s = 0; s < 4; ++s) {
            float v = T[s];
            #pragma unroll
            for (int ofs = 1; ofs < 64; ofs <<= 1) {
                float u = __shfl_down(v, ofs);
                if (lane + ofs < 64) v += u;
            }
            E[s] = v - T[s];
            Stot[s] = __shfl(v, 0);
        }
        float segOff[4];
        segOff[3] = 0.f;
        segOff[2] = Stot[3];
        segOff[1] = Stot[3] + Stot[2];
        segOff[0] = Stot[3] + Stot[2] + Stot[1];
        const float* tab = tableL[row];
        float* orow = out + (size_t)(batch * SLEN + qbase + row) * SLEN;
        #pragma unroll
        for (int s = 0; s < 4; ++s) {
            float res[4];
            #pragma unroll
            for (int i = 0; i < 4; ++i) {
                float p = ls[s][i] + E[s] + segOff[s];
                p = fminf(p, (float)(NPOS - 1));
                float pf = floorf(p);
                int fi = (int)pf;
                int ci = (int)ceilf(p);
                float w = p - pf;
                res[i] = tab[ci] * w + tab[fi] * (1.0f - w);
            }
            float4 o; o.x = res[0]; o.y = res[1]; o.z = res[2]; o.w = res[3];
            *(float4*)&orow[s * 256 + lane * 4] = o;
        }
    }
}

extern "C" void kernel_launch(void* const* d_in, const int* in_sizes, int n_in,
                              void* d_out, int out_size, void* d_ws, size_t ws_size,
                              hipStream_t stream) {
    const float* q        = (const float*)d_in[0];
    const float* k        = (const float*)d_in[1];
    const float* pos_emb  = (const float*)d_in[3];
    const int*   is_cope_k = (const int*)d_in[5];
    float* out = (float*)d_out;

    const int nk = in_sizes[1];                 // B*S*D
    const int B = in_sizes[0] / (SLEN * DDIM);
    const size_t ws_need = (size_t)nk * 2 * sizeof(unsigned short);  // khi + klo

    if (ws_size >= ws_need) {
        unsigned short* khi = (unsigned short*)d_ws;
        unsigned short* klo = khi + nk;
        int n4 = nk / 4;
        prep_kernel<<<(n4 + 255) / 256, 256, 0, stream>>>(k, khi, klo, n4);
        cope_mfma_kernel<<<B * (SLEN / QROWS), 256, 0, stream>>>(
            q, k, pos_emb, is_cope_k, khi, klo, out);
    } else {
        cope_fallback<<<B * (SLEN / FQROWS), 256, 0, stream>>>(
            q, k, pos_emb, is_cope_k, out);
    }
}

// Round 5
// 173.794 us; speedup vs baseline: 1.5955x; 1.2170x over previous
//
#include <hip/hip_runtime.h>

#define SLEN 1024
#define DDIM 64
#define NPOS 64
#define QROWS 16
#define QCOLS 256          // columns per quarter (processed right-to-left)
#define COPE_SCALE 0.125f
#define GSTR 260           // G row stride (words): 2-way max bank alias on scatter
#define TSTR 66            // table row stride: 2-way max

typedef __bf16 bf16x8 __attribute__((ext_vector_type(8)));
typedef float f32x4 __attribute__((ext_vector_type(4)));

__device__ __forceinline__ unsigned short f2bf_hi(float x) {
    unsigned u = __builtin_bit_cast(unsigned, x);
    unsigned r = u + 0x7FFFu + ((u >> 16) & 1u);
    return (unsigned short)(r >> 16);
}
__device__ __forceinline__ float bf2f(unsigned short h) {
    unsigned u = ((unsigned)h) << 16;
    return __builtin_bit_cast(float, u);
}
struct U8 { ushort4 a, b; };
__device__ __forceinline__ bf16x8 pack8(const unsigned short* s) {
    U8 u = {{s[0], s[1], s[2], s[3]}, {s[4], s[5], s[6], s[7]}};
    return __builtin_bit_cast(bf16x8, u);
}

// ---------------- prep: split k into bf16 hi + lo ----------------
__global__ __launch_bounds__(256) void prep_kernel(
    const float* __restrict__ k,
    unsigned short* __restrict__ khi,
    unsigned short* __restrict__ klo,
    int n4)
{
    int i = blockIdx.x * 256 + threadIdx.x;
    if (i >= n4) return;
    float4 v = ((const float4*)k)[i];
    ushort4 h, l;
    h.x = f2bf_hi(v.x); l.x = f2bf_hi(v.x - bf2f(h.x));
    h.y = f2bf_hi(v.y); l.y = f2bf_hi(v.y - bf2f(h.y));
    h.z = f2bf_hi(v.z); l.z = f2bf_hi(v.z - bf2f(h.z));
    h.w = f2bf_hi(v.w); l.w = f2bf_hi(v.w - bf2f(h.w));
    ((ushort4*)khi)[i] = h;
    ((ushort4*)klo)[i] = l;
}

// ---------------- main MFMA kernel ----------------
__global__ __launch_bounds__(256, 6) void cope_mfma_kernel(
    const float* __restrict__ q,
    const float* __restrict__ k,
    const float* __restrict__ pos_emb,
    const int*   __restrict__ is_cope_k,
    const unsigned short* __restrict__ khi,
    const unsigned short* __restrict__ klo,
    float*       __restrict__ out)
{
    __shared__ __align__(16) float G[QROWS * GSTR];        // 16.6 KB (one quarter)
    __shared__ __align__(16) float tableL[QROWS * TSTR];   // 4.2 KB
    __shared__ float Racc[QROWS];                          // running suffix totals

    const int t = threadIdx.x;
    const int wave = t >> 6;
    const int lane = t & 63;
    const int quad = lane >> 4;
    const int nloc = lane & 15;
    const int blk = blockIdx.x;
    const int batch = blk >> 6;           // SLEN/QROWS = 64 blocks per batch
    const int qbase = (blk & 63) * QROWS;

    if (t < QROWS) Racc[t] = 0.f;

    // ---- A fragments from q (split hi/lo): lane holds A[m=nloc][k=quad*8+j+ks*32] ----
    bf16x8 a_hi[2], a_lo[2];
    {
        const float* qrow = q + (size_t)(batch * SLEN + qbase + nloc) * DDIM + quad * 8;
        #pragma unroll
        for (int ks = 0; ks < 2; ++ks) {
            float4 v0 = *(const float4*)(qrow + ks * 32);
            float4 v1 = *(const float4*)(qrow + ks * 32 + 4);
            float xs[8] = {v0.x, v0.y, v0.z, v0.w, v1.x, v1.y, v1.z, v1.w};
            unsigned short hb[8], lb[8];
            #pragma unroll
            for (int j = 0; j < 8; ++j) {
                hb[j] = f2bf_hi(xs[j]);
                lb[j] = f2bf_hi(xs[j] - bf2f(hb[j]));
            }
            a_hi[ks] = pack8(hb);
            a_lo[ks] = pack8(lb);
        }
    }

    // ---- interp table via MFMA: table[m][n] = sum_d base[m][d] * pos_emb[d][n] ----
    {
        const int icope = *is_cope_k;   // wave-uniform
        bf16x8 t_hi[2], t_lo[2];
        if (icope) {
            t_hi[0] = a_hi[0]; t_hi[1] = a_hi[1];
            t_lo[0] = a_lo[0]; t_lo[1] = a_lo[1];
        } else {
            size_t boff = (size_t)(batch * SLEN + qbase + nloc) * DDIM + quad * 8;
            t_hi[0] = __builtin_bit_cast(bf16x8, *(const uint4*)(khi + boff));
            t_hi[1] = __builtin_bit_cast(bf16x8, *(const uint4*)(khi + boff + 32));
            t_lo[0] = __builtin_bit_cast(bf16x8, *(const uint4*)(klo + boff));
            t_lo[1] = __builtin_bit_cast(bf16x8, *(const uint4*)(klo + boff + 32));
        }
        bf16x8 p_hi[2];
        #pragma unroll
        for (int ks = 0; ks < 2; ++ks) {
            unsigned short hb[8];
            #pragma unroll
            for (int j = 0; j < 8; ++j) {
                float pv = pos_emb[(quad * 8 + j + ks * 32) * NPOS + wave * 16 + nloc];
                hb[j] = f2bf_hi(pv);
            }
            p_hi[ks] = pack8(hb);
        }
        f32x4 tacc = {0.f, 0.f, 0.f, 0.f};
        tacc = __builtin_amdgcn_mfma_f32_16x16x32_bf16(t_hi[0], p_hi[0], tacc, 0, 0, 0);
        tacc = __builtin_amdgcn_mfma_f32_16x16x32_bf16(t_lo[0], p_hi[0], tacc, 0, 0, 0);
        tacc = __builtin_amdgcn_mfma_f32_16x16x32_bf16(t_hi[1], p_hi[1], tacc, 0, 0, 0);
        tacc = __builtin_amdgcn_mfma_f32_16x16x32_bf16(t_lo[1], p_hi[1], tacc, 0, 0, 0);
        #pragma unroll
        for (int reg = 0; reg < 4; ++reg)
            tableL[(quad * 4 + reg) * TSTR + wave * 16 + nloc] = tacc[reg];
    }

    // ---- quarters right-to-left; stop when every row's suffix total >= 63 ----
    int remaining = 0;   // quarters left un-processed when we break (all clamp)
    for (int qi = 3; qi >= 0; --qi) {
        // Phase B: QK^T for this quarter (each wave: 4 of 16 tiles)
        #pragma unroll
        for (int i = 0; i < 4; ++i) {
            const int tl = wave * 4 + i;
            size_t boff = (size_t)(batch * SLEN + qi * QCOLS + tl * 16 + nloc) * DDIM + quad * 8;
            uint4 bh0 = *(const uint4*)(khi + boff);
            uint4 bh1 = *(const uint4*)(khi + boff + 32);
            uint4 bl0 = *(const uint4*)(klo + boff);
            uint4 bl1 = *(const uint4*)(klo + boff + 32);
            f32x4 acc = {0.f, 0.f, 0.f, 0.f};
            acc = __builtin_amdgcn_mfma_f32_16x16x32_bf16(a_hi[0], __builtin_bit_cast(bf16x8, bh0), acc, 0, 0, 0);
            acc = __builtin_amdgcn_mfma_f32_16x16x32_bf16(a_lo[0], __builtin_bit_cast(bf16x8, bh0), acc, 0, 0, 0);
            acc = __builtin_amdgcn_mfma_f32_16x16x32_bf16(a_hi[0], __builtin_bit_cast(bf16x8, bl0), acc, 0, 0, 0);
            acc = __builtin_amdgcn_mfma_f32_16x16x32_bf16(a_hi[1], __builtin_bit_cast(bf16x8, bh1), acc, 0, 0, 0);
            acc = __builtin_amdgcn_mfma_f32_16x16x32_bf16(a_lo[1], __builtin_bit_cast(bf16x8, bh1), acc, 0, 0, 0);
            acc = __builtin_amdgcn_mfma_f32_16x16x32_bf16(a_hi[1], __builtin_bit_cast(bf16x8, bl1), acc, 0, 0, 0);
            // C/D layout: n = nloc (col), m = quad*4+reg (row)
            #pragma unroll
            for (int reg = 0; reg < 4; ++reg) {
                float x = acc[reg] * COPE_SCALE;
                float g = __builtin_amdgcn_rcpf(1.0f + __expf(-x));
                G[(quad * 4 + reg) * GSTR + tl * 16 + nloc] = g;
            }
        }
        __syncthreads();

        // Phase D: suffix scan + interp + store (each wave: 4 rows; lane: 4 cols)
        #pragma unroll
        for (int rep = 0; rep < 4; ++rep) {
            const int row = wave * 4 + rep;
            const float roff = Racc[row];
            float4 gv = *(const float4*)&G[row * GSTR + lane * 4];
            float ls3 = gv.w;
            float ls2 = gv.z + ls3;
            float ls1 = gv.y + ls2;
            float ls0 = gv.x + ls1;
            const float T = ls0;
            float v = T;
            #pragma unroll
            for (int ofs = 1; ofs < 64; ofs <<= 1) {
                float u = __shfl_down(v, ofs);
                if (lane + ofs < 64) v += u;
            }
            if (lane == 0) Racc[row] = roff + v;   // quarter total accumulates
            const float E = (v - T) + roff;

            const float tabv = tableL[row * TSTR + lane];   // tab[lane] in lane
            float dtabv = __shfl_down(tabv, 1) - tabv;      // tab[lane+1]-tab[lane]
            if (lane == 63) dtabv = 0.f;
            float ls[4] = {ls0, ls1, ls2, ls3};
            float res[4];
            #pragma unroll
            for (int i = 0; i < 4; ++i) {
                float p = ls[i] + E;
                p = fminf(p, (float)(NPOS - 1));
                float pf = floorf(p);
                int fi = (int)pf;
                float w = p - pf;
                float tf = __shfl(tabv, fi);
                float td = __shfl(dtabv, fi);
                res[i] = tf + w * td;
            }
            float* orow = out + (size_t)(batch * SLEN + qbase + row) * SLEN + qi * QCOLS + lane * 4;
            f32x4 o = {res[0], res[1], res[2], res[3]};
            __builtin_nontemporal_store(o, (f32x4*)orow);
        }
        __syncthreads();

        // done-check (uniform across block): all rows clamped?
        float mn = Racc[0];
        #pragma unroll
        for (int r = 1; r < QROWS; ++r) mn = fminf(mn, Racc[r]);
        if (mn >= (float)(NPOS - 1)) { remaining = qi; break; }
    }

    // ---- broadcast region: cols 0 .. remaining*QCOLS-1 are exactly tab[63] ----
    if (remaining > 0) {
        const int ncols = remaining * QCOLS;
        #pragma unroll
        for (int rep = 0; rep < 4; ++rep) {
            const int row = wave * 4 + rep;
            const float v63 = tableL[row * TSTR + (NPOS - 1)];
            f32x4 bv = {v63, v63, v63, v63};
            float* orow = out + (size_t)(batch * SLEN + qbase + row) * SLEN;
            for (int c = lane * 4; c < ncols; c += 256)
                __builtin_nontemporal_store(bv, (f32x4*)(orow + c));
        }
    }
}

// ---------------- fallback: round-1 fp32 kernel (used if ws too small) ----------------
#define KTILE 128
#define KPAD 68
#define NTILES (SLEN / KTILE)
#define FQROWS 8

__global__ __launch_bounds__(256) void cope_fallback(
    const float* __restrict__ q,
    const float* __restrict__ k,
    const float* __restrict__ pos_emb,
    const int*   __restrict__ is_cope_k,
    float*       __restrict__ out)
{
    __shared__ __align__(16) float smem[KTILE * KPAD];
    __shared__ __align__(16) float qT[DDIM][FQROWS];
    __shared__ __align__(16) float baseT[DDIM][FQROWS];
    __shared__ __align__(16) float tableL2[FQROWS][NPOS];

    const int t = threadIdx.x;
    const int blk = blockIdx.x;
    const int batch = blk / (SLEN / FQROWS);
    const int qbase = (blk % (SLEN / FQROWS)) * FQROWS;
    const float* bsrc = (*is_cope_k) ? q : k;

    for (int i = t; i < FQROWS * DDIM; i += 256) {
        int r = i >> 6, d = i & 63;
        size_t gi = (size_t)(batch * SLEN + qbase + r) * DDIM + d;
        qT[d][r] = q[gi];
        baseT[d][r] = bsrc[gi];
    }
    __syncthreads();
    for (int i = t; i < FQROWS * NPOS; i += 256) {
        int r = i >> 6, n = i & 63;
        float a = 0.f;
        #pragma unroll
        for (int d = 0; d < DDIM; ++d) a += baseT[d][r] * pos_emb[d * NPOS + n];
        tableL2[r][n] = a;
    }
    const int jl = t & 127;
    const int qg = t >> 7;
    float acc[4][NTILES];
    #pragma unroll
    for (int r = 0; r < 4; ++r)
        #pragma unroll
        for (int tl = 0; tl < NTILES; ++tl) acc[r][tl] = 0.f;
    float (*kT)[KPAD] = (float (*)[KPAD])smem;
    const float* kbatch = k + (size_t)batch * SLEN * DDIM;
    #pragma unroll
    for (int tile = 0; tile < NTILES; ++tile) {
        __syncthreads();
        const float4* src = (const float4*)(kbatch + tile * KTILE * DDIM);
        #pragma unroll
        for (int i = 0; i < (KTILE * DDIM / 4) / 256; ++i) {
            int idx = i * 256 + t;
            int row = (idx * 4) >> 6;
            int col = (idx * 4) & 63;
            float4 vv = src[idx];
            *(float4*)&kT[row][col] = vv;
        }
        __syncthreads();
        #pragma unroll
        for (int d = 0; d < DDIM; d += 4) {
            float4 kv = *(const float4*)&kT[jl][d];
            float4 q0 = *(const float4*)&qT[d + 0][qg * 4];
            float4 q1 = *(const float4*)&qT[d + 1][qg * 4];
            float4 q2 = *(const float4*)&qT[d + 2][qg * 4];
            float4 q3 = *(const float4*)&qT[d + 3][qg * 4];
            acc[0][tile] += kv.x * q0.x + kv.y * q1.x + kv.z * q2.x + kv.w * q3.x;
            acc[1][tile] += kv.x * q0.y + kv.y * q1.y + kv.z * q2.y + kv.w * q3.y;
            acc[2][tile] += kv.x * q0.z + kv.y * q1.z + kv.z * q2.z + kv.w * q3.z;
            acc[3][tile] += kv.x * q0.w + kv.y * q1.w + kv.z * q2.w + kv.w * q3.w;
        }
    }
    __syncthreads();
    float (*G2)[SLEN] = (float (*)[SLEN])smem;
    #pragma unroll
    for (int r = 0; r < 4; ++r)
        #pragma unroll
        for (int tl = 0; tl < NTILES; ++tl) {
            float x = acc[r][tl] * COPE_SCALE;
            G2[qg * 4 + r][tl * KTILE + jl] = 1.0f / (1.0f + __expf(-x));
        }
    __syncthreads();
    const int wave = t >> 6;
    const int lane = t & 63;
    #pragma unroll
    for (int rep = 0; rep < 2; ++rep) {
        const int row = wave * 2 + rep;
        float g4[4][4];
        #pragma unroll
        for (int s = 0; s < 4; ++s) {
            float4 v = *(const float4*)&G2[row][s * 256 + lane * 4];
            g4[s][0] = v.x; g4[s][1] = v.y; g4[s][2] = v.z; g4[s][3] = v.w;
        }
        float ls[4][4], T[4];
        #pragma unroll
        for (int s = 0; s < 4; ++s) {
            float a = 0.f;
            #pragma unroll
            for (int i = 3; i >= 0; --i) { a += g4[s][i]; ls[s][i] = a; }
            T[s] = a;
        }
        float E[4], Stot[4];
        #pragma unroll
        for (int s = 0; s < 4; ++s) {
            float v = T[s];
            #pragma unroll
            for (int ofs = 1; ofs < 64; ofs <<= 1) {
                float u = __shfl_down(v, ofs);
                if (lane + ofs < 64) v += u;
            }
            E[s] = v - T[s];
            Stot[s] = __shfl(v, 0);
        }
        float segOff[4];
        segOff[3] = 0.f;
        segOff[2] = Stot[3];
        segOff[1] = Stot[3] + Stot[2];
        segOff[0] = Stot[3] + Stot[2] + Stot[1];
        const float* tab = tableL2[row];
        float* orow = out + (size_t)(batch * SLEN + qbase + row) * SLEN;
        #pragma unroll
        for (int s = 0; s < 4; ++s) {
            float res[4];
            #pragma unroll
            for (int i = 0; i < 4; ++i) {
                float p = ls[s][i] + E[s] + segOff[s];
                p = fminf(p, (float)(NPOS - 1));
                float pf = floorf(p);
                int fi = (int)pf;
                int ci = (int)ceilf(p);
                float w = p - pf;
                res[i] = tab[ci] * w + tab[fi] * (1.0f - w);
            }
            float4 o; o.x = res[0]; o.y = res[1]; o.z = res[2]; o.w = res[3];
            *(float4*)&orow[s * 256 + lane * 4] = o;
        }
    }
}

extern "C" void kernel_launch(void* const* d_in, const int* in_sizes, int n_in,
                              void* d_out, int out_size, void* d_ws, size_t ws_size,
                              hipStream_t stream) {
    const float* q        = (const float*)d_in[0];
    const float* k        = (const float*)d_in[1];
    const float* pos_emb  = (const float*)d_in[3];
    const int*   is_cope_k = (const int*)d_in[5];
    float* out = (float*)d_out;

    const int nk = in_sizes[1];                 // B*S*D
    const int B = in_sizes[0] / (SLEN * DDIM);
    const size_t ws_need = (size_t)nk * 2 * sizeof(unsigned short);  // khi + klo

    if (ws_size >= ws_need) {
        unsigned short* khi = (unsigned short*)d_ws;
        unsigned short* klo = khi + nk;
        int n4 = nk / 4;
        prep_kernel<<<(n4 + 255) / 256, 256, 0, stream>>>(k, khi, klo, n4);
        cope_mfma_kernel<<<B * (SLEN / QROWS), 256, 0, stream>>>(
            q, k, pos_emb, is_cope_k, khi, klo, out);
    } else {
        cope_fallback<<<B * (SLEN / FQROWS), 256, 0, stream>>>(
            q, k, pos_emb, is_cope_k, out);
    }
}